// Round 1
// baseline (8411.333 us; speedup 1.0000x reference)
//
#include <hip/hip_runtime.h>
#include <hip/hip_bf16.h>

#define NN 10000
#define EE 160000
#define NFEAT 2
#define HIDW 128
#define EMB 64
#define EDGE_IN 133
#define NODE_IN 130

// ---------------- dtype detection ----------------
// If inputs are bf16, dword bits[8:15] of `distance` (uniform [0,1)) are the
// sign+exponent byte of element 0: ~[0x2E,0x3F]. If f32, they're random
// mantissa bits. Majority vote over 64 dwords.
__global__ void detect_kernel(const unsigned int* __restrict__ bits, int* __restrict__ flag) {
    int cnt = 0;
    for (int i = 0; i < 64; ++i) {
        unsigned b = (bits[i] >> 8) & 0xFF;
        if (b >= 0x1C && b <= 0x41) ++cnt;
    }
    *flag = (cnt >= 32) ? 1 : 0;
}

__global__ void cvt_kernel(const void* __restrict__ in, float* __restrict__ out, int n,
                           const int* __restrict__ flag) {
    const int isbf = *flag;
    int i = blockIdx.x * blockDim.x + threadIdx.x;
    const int stride = gridDim.x * blockDim.x;
    if (isbf) {
        const __hip_bfloat16* p = (const __hip_bfloat16*)in;
        for (; i < n; i += stride) out[i] = __bfloat162float(p[i]);
    } else {
        const float* p = (const float*)in;
        for (; i < n; i += stride) out[i] = p[i];
    }
}

// ---------------- init MLP: nf(2) -> 128 relu -> 64 relu ----------------
__global__ __launch_bounds__(256) void init_kernel(
    const float* __restrict__ nf, const float* __restrict__ w1, const float* __restrict__ b1,
    const float* __restrict__ w2, const float* __restrict__ b2, float* __restrict__ h) {
    __shared__ float s_hid[4][HIDW];
    const int wave = threadIdx.x >> 6, lane = threadIdx.x & 63;
    for (int base = blockIdx.x * 4; base < NN; base += gridDim.x * 4) {
        const int node = base + wave;  // NN % 4 == 0 -> always valid
        const float f0 = nf[node * 2 + 0], f1 = nf[node * 2 + 1];
        const int o0 = lane, o1 = lane + 64;
        float a0 = b1[o0] + f0 * w1[o0] + f1 * w1[HIDW + o0];
        float a1 = b1[o1] + f0 * w1[o1] + f1 * w1[HIDW + o1];
        s_hid[wave][o0] = fmaxf(a0, 0.f);
        s_hid[wave][o1] = fmaxf(a1, 0.f);
        __syncthreads();
        float acc = b2[lane];
        for (int k = 0; k < HIDW; ++k) acc = fmaf(s_hid[wave][k], w2[k * EMB + lane], acc);
        h[node * EMB + lane] = fmaxf(acc, 0.f);
        __syncthreads();
    }
}

// ------------- edge MLP fused with segment-sum scatter -------------
// e_in = [nf[dst](2), h[dst](64), nf[src](2), h[src](64), d(1)] -> 133
__global__ __launch_bounds__(256) void edge_kernel(
    const float* __restrict__ h, const float* __restrict__ nf, const float* __restrict__ dist,
    const int* __restrict__ src, const int* __restrict__ dst,
    const float* __restrict__ w1, const float* __restrict__ b1,
    const float* __restrict__ w2, const float* __restrict__ b2, float* __restrict__ agg) {
    __shared__ float s_in[4][EDGE_IN + 3];
    __shared__ float s_hid[4][HIDW];
    const int wave = threadIdx.x >> 6, lane = threadIdx.x & 63;
    for (int base = blockIdx.x * 4; base < EE; base += gridDim.x * 4) {
        const int e = base + wave;  // EE % 4 == 0 -> always valid
        const int s = src[e], t = dst[e];
        s_in[wave][2 + lane]  = h[t * EMB + lane];
        s_in[wave][68 + lane] = h[s * EMB + lane];
        if (lane < 2) {
            s_in[wave][lane]      = nf[t * 2 + lane];
            s_in[wave][66 + lane] = nf[s * 2 + lane];
        }
        if (lane == 0) s_in[wave][132] = dist[e];
        __syncthreads();
        float a0 = b1[lane], a1 = b1[lane + 64];
        for (int k = 0; k < EDGE_IN; ++k) {
            const float x = s_in[wave][k];
            a0 = fmaf(x, w1[k * HIDW + lane], a0);
            a1 = fmaf(x, w1[k * HIDW + 64 + lane], a1);
        }
        s_hid[wave][lane]      = fmaxf(a0, 0.f);
        s_hid[wave][lane + 64] = fmaxf(a1, 0.f);
        __syncthreads();
        float acc = b2[lane];
        for (int k = 0; k < HIDW; ++k) acc = fmaf(s_hid[wave][k], w2[k * EMB + lane], acc);
        atomicAdd(&agg[t * EMB + lane], fmaxf(acc, 0.f));
        __syncthreads();
    }
}

// ------------- node MLP: [h(64), nf(2), agg(64)] -> 128 relu -> 64 relu -------------
__global__ __launch_bounds__(256) void node_kernel(
    const float* __restrict__ h, const float* __restrict__ nf, const float* __restrict__ agg,
    const float* __restrict__ w1, const float* __restrict__ b1,
    const float* __restrict__ w2, const float* __restrict__ b2, float* __restrict__ hout) {
    __shared__ float s_in[4][NODE_IN + 2];
    __shared__ float s_hid[4][HIDW];
    const int wave = threadIdx.x >> 6, lane = threadIdx.x & 63;
    for (int base = blockIdx.x * 4; base < NN; base += gridDim.x * 4) {
        const int node = base + wave;
        s_in[wave][lane]      = h[node * EMB + lane];
        s_in[wave][66 + lane] = agg[node * EMB + lane];
        if (lane < 2) s_in[wave][64 + lane] = nf[node * 2 + lane];
        __syncthreads();
        float a0 = b1[lane], a1 = b1[lane + 64];
        for (int k = 0; k < NODE_IN; ++k) {
            const float x = s_in[wave][k];
            a0 = fmaf(x, w1[k * HIDW + lane], a0);
            a1 = fmaf(x, w1[k * HIDW + 64 + lane], a1);
        }
        s_hid[wave][lane]      = fmaxf(a0, 0.f);
        s_hid[wave][lane + 64] = fmaxf(a1, 0.f);
        __syncthreads();
        float acc = b2[lane];
        for (int k = 0; k < HIDW; ++k) acc = fmaf(s_hid[wave][k], w2[k * EMB + lane], acc);
        hout[node * EMB + lane] = fmaxf(acc, 0.f);
        __syncthreads();
    }
}

// ------------- classifier: c_in(133) -> 64 relu -> 1 sigmoid -------------
__global__ __launch_bounds__(256) void cls_kernel(
    const float* __restrict__ h, const float* __restrict__ nf, const float* __restrict__ dist,
    const int* __restrict__ src, const int* __restrict__ dst,
    const float* __restrict__ w1, const float* __restrict__ b1,
    const float* __restrict__ w2, const float* __restrict__ b2,
    void* __restrict__ out, const int* __restrict__ flag) {
    __shared__ float s_in[4][EDGE_IN + 3];
    const int wave = threadIdx.x >> 6, lane = threadIdx.x & 63;
    const int isbf = *flag;
    for (int base = blockIdx.x * 4; base < EE; base += gridDim.x * 4) {
        const int e = base + wave;
        const int s = src[e], t = dst[e];
        s_in[wave][2 + lane]  = h[t * EMB + lane];
        s_in[wave][68 + lane] = h[s * EMB + lane];
        if (lane < 2) {
            s_in[wave][lane]      = nf[t * 2 + lane];
            s_in[wave][66 + lane] = nf[s * 2 + lane];
        }
        if (lane == 0) s_in[wave][132] = dist[e];
        __syncthreads();
        float acc = b1[lane];
        for (int k = 0; k < EDGE_IN; ++k) acc = fmaf(s_in[wave][k], w1[k * EMB + lane], acc);
        const float hid = fmaxf(acc, 0.f);
        float p = hid * w2[lane];
        for (int off = 32; off > 0; off >>= 1) p += __shfl_down(p, off);
        if (lane == 0) {
            const float val = p + b2[0];
            const float sg = 1.f / (1.f + __expf(-val));
            if (isbf) ((__hip_bfloat16*)out)[e] = __float2bfloat16(sg);
            else      ((float*)out)[e] = sg;
        }
        __syncthreads();
    }
}

extern "C" void kernel_launch(void* const* d_in, const int* in_sizes, int n_in,
                              void* d_out, int out_size, void* d_ws, size_t ws_size,
                              hipStream_t stream) {
    // inputs in setup_inputs() order
    const void* in_nf    = d_in[0];
    const void* in_dist  = d_in[1];
    const int*  src      = (const int*)d_in[2];
    const int*  dst      = (const int*)d_in[3];
    const void* in_iw1   = d_in[4];
    const void* in_ib1   = d_in[5];
    const void* in_iw2   = d_in[6];
    const void* in_ib2   = d_in[7];
    const void* in_ew1   = d_in[8];
    const void* in_eb1   = d_in[9];
    const void* in_ew2   = d_in[10];
    const void* in_eb2   = d_in[11];
    const void* in_nw1   = d_in[12];
    const void* in_nb1   = d_in[13];
    const void* in_nw2   = d_in[14];
    const void* in_nb2   = d_in[15];
    const void* in_cw1   = d_in[16];
    const void* in_cb1   = d_in[17];
    const void* in_cw2   = d_in[18];
    const void* in_cb2   = d_in[19];

    float* p = (float*)d_ws;
    float* h0   = p; p += NN * EMB;
    float* h1   = p; p += NN * EMB;
    float* agg  = p; p += NN * EMB;
    float* nf   = p; p += NN * NFEAT;
    float* dist = p; p += EE;
    float* iw1  = p; p += NFEAT * HIDW;
    float* ib1  = p; p += HIDW;
    float* iw2  = p; p += HIDW * EMB;
    float* ib2  = p; p += EMB;
    float* ew1  = p; p += EDGE_IN * HIDW;
    float* eb1  = p; p += HIDW;
    float* ew2  = p; p += HIDW * EMB;
    float* eb2  = p; p += EMB;
    float* nw1  = p; p += NODE_IN * HIDW;
    float* nb1  = p; p += HIDW;
    float* nw2  = p; p += HIDW * EMB;
    float* nb2  = p; p += EMB;
    float* cw1  = p; p += EDGE_IN * EMB;
    float* cb1  = p; p += EMB;
    float* cw2  = p; p += EMB;
    float* cb2  = p; p += 1;
    int* flag   = (int*)p;

    detect_kernel<<<1, 1, 0, stream>>>((const unsigned int*)in_dist, flag);

    struct CvtJob { const void* src; float* dst; int n; };
    const CvtJob jobs[] = {
        {in_nf, nf, NN * NFEAT}, {in_dist, dist, EE},
        {in_iw1, iw1, NFEAT * HIDW}, {in_ib1, ib1, HIDW}, {in_iw2, iw2, HIDW * EMB}, {in_ib2, ib2, EMB},
        {in_ew1, ew1, EDGE_IN * HIDW}, {in_eb1, eb1, HIDW}, {in_ew2, ew2, HIDW * EMB}, {in_eb2, eb2, EMB},
        {in_nw1, nw1, NODE_IN * HIDW}, {in_nb1, nb1, HIDW}, {in_nw2, nw2, HIDW * EMB}, {in_nb2, nb2, EMB},
        {in_cw1, cw1, EDGE_IN * EMB}, {in_cb1, cb1, EMB}, {in_cw2, cw2, EMB}, {in_cb2, cb2, 1},
    };
    for (const auto& j : jobs) {
        int blocks = (j.n + 255) / 256;
        if (blocks > 256) blocks = 256;
        cvt_kernel<<<blocks, 256, 0, stream>>>(j.src, j.dst, j.n, flag);
    }

    init_kernel<<<NN / 4, 256, 0, stream>>>(nf, iw1, ib1, iw2, ib2, h0);

    float* hc = h0;
    float* hn = h1;
    for (int it = 0; it < 16; ++it) {
        hipMemsetAsync(agg, 0, (size_t)NN * EMB * sizeof(float), stream);
        edge_kernel<<<2048, 256, 0, stream>>>(hc, nf, dist, src, dst, ew1, eb1, ew2, eb2, agg);
        node_kernel<<<NN / 4, 256, 0, stream>>>(hc, nf, agg, nw1, nb1, nw2, nb2, hn);
        float* tmp = hc; hc = hn; hn = tmp;
    }

    cls_kernel<<<2048, 256, 0, stream>>>(hc, nf, dist, src, dst, cw1, cb1, cw2, cb2, d_out, flag);
}